// Round 6
// baseline (202.780 us; speedup 1.0000x reference)
//
#include <hip/hip_runtime.h>

typedef __bf16 bf16;
typedef __bf16 bf16x8 __attribute__((ext_vector_type(8)));
typedef __bf16 bf16x4v __attribute__((ext_vector_type(4)));
typedef float  f32x4  __attribute__((ext_vector_type(4)));

#define NROWS 8192
#define DDIM  256
#define TAU_INV 2.0f
#define KAPPA 2.8853900817779268f   // TAU_INV * log2(e): A pre-scale so exp(s*2) = exp2(acc)
#define LN2 0.6931471805599453f
#define EPS 1e-8f

#define AS1C(p) ((const __attribute__((address_space(1))) void*)(p))
#define AS3(p)  ((__attribute__((address_space(3))) void*)(p))

// ---------------- cast 4 weight matrices fp32 -> bf16 ----------------
__global__ __launch_bounds__(256) void cast4_kernel(
    const float* __restrict__ s0, const float* __restrict__ s1,
    const float* __restrict__ s2, const float* __restrict__ s3,
    bf16* __restrict__ dst) {
  const float* s = blockIdx.y == 0 ? s0 : blockIdx.y == 1 ? s1 : blockIdx.y == 2 ? s2 : s3;
  bf16* d = dst + (size_t)blockIdx.y * 65536;
  int i = blockIdx.x * 256 + threadIdx.x;
  f32x4 v = ((const f32x4*)s)[i];
  bf16x4v o;
  o[0] = (bf16)v[0]; o[1] = (bf16)v[1]; o[2] = (bf16)v[2]; o[3] = (bf16)v[3];
  ((bf16x4v*)d)[i] = o;
}

// ---------------- fused cast + 2-layer MLP + row-normalize ----------------
// grid (NROWS/64, 2), block 256. Wave w owns rows [w*16, w*16+16).
// view 0 output (A side of the big GEMM) is scaled by KAPPA.
__global__ __launch_bounds__(256) void mlp_norm_kernel(
    const float* __restrict__ z1f, const float* __restrict__ z2f,
    const bf16* __restrict__ wq,
    const float* __restrict__ b1c, const float* __restrict__ b2c,
    const float* __restrict__ b1k, const float* __restrict__ b2k,
    bf16* __restrict__ outA, bf16* __restrict__ outB)
{
  const int view = blockIdx.y;
  const float* xf = view ? z2f : z1f;
  const bf16*  w1 = wq + (size_t)view * 131072;
  const bf16*  w2 = w1 + 65536;
  const float* b1 = view ? b1k : b1c;
  const float* b2 = view ? b2k : b2c;
  bf16* out = view ? outB : outA;
  const float osc = view ? 1.0f : KAPPA;

  __shared__ __align__(16) char xs[64 * 512];  // 64 rows x 256 bf16, XOR-swizzled

  const int tid  = threadIdx.x;
  const int lane = tid & 63;
  const int w    = tid >> 6;
  const int c    = lane & 15;
  const int g    = lane >> 4;
  const int r0   = blockIdx.x * 64;

#pragma unroll
  for (int k = 0; k < 8; ++k) {
    int gid = k * 256 + tid;
    int row = gid >> 5, cg = gid & 31;
    const f32x4* p = (const f32x4*)(xf + (size_t)(r0 + row) * DDIM + cg * 8);
    f32x4 v0 = p[0], v1 = p[1];
    bf16x8 o;
    o[0] = (bf16)v0[0]; o[1] = (bf16)v0[1]; o[2] = (bf16)v0[2]; o[3] = (bf16)v0[3];
    o[4] = (bf16)v1[0]; o[5] = (bf16)v1[1]; o[6] = (bf16)v1[2]; o[7] = (bf16)v1[3];
    *(bf16x8*)(xs + row * 512 + ((cg * 16) ^ ((row & 7) << 4))) = o;
  }
  __syncthreads();

  float b1v[16], b2v[16];
#pragma unroll
  for (int ct = 0; ct < 16; ++ct) { b1v[ct] = b1[ct * 16 + c]; b2v[ct] = b2[ct * 16 + c]; }

  const int arow = w * 16 + c;
  const int aswz = (arow & 7) << 4;

  f32x4 acc[16];
  const f32x4 fz = {0.f, 0.f, 0.f, 0.f};
#pragma unroll
  for (int ct = 0; ct < 16; ++ct) acc[ct] = fz;

#pragma unroll
  for (int ks = 0; ks < 8; ++ks) {
    bf16x8 af = *(const bf16x8*)(xs + arow * 512 + ((ks * 64 + g * 16) ^ aswz));
#pragma unroll
    for (int ct = 0; ct < 16; ++ct) {
      bf16x8 bfv = *(const bf16x8*)(w1 + (size_t)(ct * 16 + c) * DDIM + ks * 32 + g * 8);
      acc[ct] = __builtin_amdgcn_mfma_f32_16x16x32_bf16(af, bfv, acc[ct], 0, 0, 0);
    }
  }

#pragma unroll
  for (int ct = 0; ct < 16; ++ct) {
#pragma unroll
    for (int r = 0; r < 4; ++r) {
      float pre = acc[ct][r] + b1v[ct];
      float h = pre > 0.0f ? pre : (__expf(pre) - 1.0f);
      int row_l = w * 16 + g * 4 + r;
      int cb = (ct * 16 + c) * 2;
      *(bf16*)(xs + row_l * 512 + (cb ^ ((row_l & 7) << 4))) = (bf16)h;
    }
  }

#pragma unroll
  for (int ct = 0; ct < 16; ++ct) acc[ct] = fz;

#pragma unroll
  for (int ks = 0; ks < 8; ++ks) {
    bf16x8 af = *(const bf16x8*)(xs + arow * 512 + ((ks * 64 + g * 16) ^ aswz));
#pragma unroll
    for (int ct = 0; ct < 16; ++ct) {
      bf16x8 bfv = *(const bf16x8*)(w2 + (size_t)(ct * 16 + c) * DDIM + ks * 32 + g * 8);
      acc[ct] = __builtin_amdgcn_mfma_f32_16x16x32_bf16(af, bfv, acc[ct], 0, 0, 0);
    }
  }

  float ss[4] = {0.f, 0.f, 0.f, 0.f};
#pragma unroll
  for (int ct = 0; ct < 16; ++ct)
#pragma unroll
    for (int r = 0; r < 4; ++r) {
      float z = acc[ct][r] + b2v[ct];
      acc[ct][r] = z;
      ss[r] += z * z;
    }
#pragma unroll
  for (int m = 1; m < 16; m <<= 1)
#pragma unroll
    for (int r = 0; r < 4; ++r) ss[r] += __shfl_xor(ss[r], m, 64);

  float rinv[4];
#pragma unroll
  for (int r = 0; r < 4; ++r) rinv[r] = osc / sqrtf(ss[r]);

#pragma unroll
  for (int ct = 0; ct < 16; ++ct)
#pragma unroll
    for (int r = 0; r < 4; ++r) {
      int grow = r0 + w * 16 + g * 4 + r;
      out[(size_t)grow * DDIM + ct * 16 + c] = (bf16)(acc[ct][r] * rinv[r]);
    }
}

// ---------------- flash-style LSE: A-in-registers, B-tile loop ----------------
// grid 512 = 32 rb x 16 cs (XCD-patched). block 256 (4 waves); wave owns 64 rows.
// A is pre-scaled by KAPPA so sum += exp2(acc) directly (no mul).
__global__ __launch_bounds__(256, 2) void lse_kernel(
    const bf16* __restrict__ A, const bf16* __restrict__ B,
    float* __restrict__ partial, float* __restrict__ diagdot)
{
  __shared__ __align__(16) char lds[65536];

  const int fid = blockIdx.x;
  const int xcd = fid & 7;
  const int l   = fid >> 3;
  const int rb  = (xcd >> 1) * 8 + (l >> 3);   // 8rb x 8cs patch per XCD: 3 MB <= L2
  const int cs  = (xcd & 1) * 8 + (l & 7);

  const int tid  = threadIdx.x;
  const int lane = tid & 63;
  const int w    = tid >> 6;
  const int c    = lane & 15;
  const int g    = lane >> 4;
  const int brow  = rb * 256;
  const int bcol0 = cs * 512;
  const int wrowg = brow + w * 64;             // wave's first global row
  const int td    = 4 * (rb & 1) + w;          // diag tile index (if diagblk)
  const bool diagblk = (cs == (rb >> 1));
  const int rswz  = (c & 7) << 4;

#define STAGEB(ttt)                                                                  \
  {                                                                                  \
    const int bsel_ = ((ttt) & 1) * 32768;                                           \
    _Pragma("unroll")                                                                \
    for (int it = 0; it < 8; ++it) {                                                 \
      int slot = it * 256 + tid;                                                     \
      int row = slot >> 5, q = slot & 31;                                            \
      const bf16* src = B + (size_t)(bcol0 + (ttt) * 64 + row) * DDIM                \
                        + ((q ^ (row & 7)) << 3);                                    \
      __builtin_amdgcn_global_load_lds(AS1C(src),                                    \
          AS3(lds + bsel_ + (it * 256 + w * 64) * 16), 16, 0, 0);                    \
    }                                                                                \
  }

  STAGEB(0);

  // A fragments: 64 rows x K=256 per wave, persistent in registers (128 VGPR)
  bf16x8 af[4][8];
#pragma unroll
  for (int mt = 0; mt < 4; ++mt)
#pragma unroll
    for (int kk = 0; kk < 8; ++kk)
      af[mt][kk] = *(const bf16x8*)(A + (size_t)(wrowg + mt * 16 + c) * DDIM + kk * 32 + g * 8);

  STAGEB(1);
  asm volatile("s_waitcnt vmcnt(8)" ::: "memory");   // A + B0 landed; B1 in flight
  __builtin_amdgcn_s_barrier();

  float rs[4][4];
#pragma unroll
  for (int mt = 0; mt < 4; ++mt)
#pragma unroll
    for (int r = 0; r < 4; ++r) rs[mt][r] = 0.f;

  const f32x4 fz = {0.f, 0.f, 0.f, 0.f};

#pragma unroll
  for (int t = 0; t < 8; ++t) {
    const char* bb = lds + (t & 1) * 32768;
    f32x4 acc[4][4];
#pragma unroll
    for (int mt = 0; mt < 4; ++mt)
#pragma unroll
      for (int nt = 0; nt < 4; ++nt) acc[mt][nt] = fz;

#pragma unroll
    for (int kk = 0; kk < 8; ++kk) {
      bf16x8 bv[4];
#pragma unroll
      for (int nt = 0; nt < 4; ++nt)
        bv[nt] = *(const bf16x8*)(bb + (nt * 16 + c) * 512 + ((kk * 64 + g * 16) ^ rswz));
#pragma unroll
      for (int mt = 0; mt < 4; ++mt)
#pragma unroll
        for (int nt = 0; nt < 4; ++nt)
          acc[mt][nt] = __builtin_amdgcn_mfma_f32_16x16x32_bf16(af[mt][kk], bv[nt], acc[mt][nt], 0, 0, 0);
    }

    // double-buffer handoff: overlap exp-fold with next-next tile staging
    if (t < 7) {
      __builtin_amdgcn_s_barrier();              // all waves done reading buf[t&1]
      if (t < 6) STAGEB(t + 2);                  // overwrite buf[t&1]
    }

    // diag extraction — STATIC vector indices only (rule #20)
    if (diagblk && t == td && (c >> 2) == g) {
#pragma unroll
      for (int mt = 0; mt < 4; ++mt) {
        f32x4 a = acc[mt][mt];
        int r = c & 3;
        float dv = (r == 0) ? a[0] : (r == 1) ? a[1] : (r == 2) ? a[2] : a[3];
        diagdot[wrowg + mt * 16 + c] = dv;
      }
    }

    // fold: per-lane partial row sums; acc is already kappa*s -> exp2 direct
#pragma unroll
    for (int mt = 0; mt < 4; ++mt)
#pragma unroll
      for (int nt = 0; nt < 4; ++nt)
#pragma unroll
        for (int r = 0; r < 4; ++r)
          rs[mt][r] += __builtin_amdgcn_exp2f(acc[mt][nt][r]);

    if (t < 7) {
      if (t < 6) { asm volatile("s_waitcnt vmcnt(8)" ::: "memory"); }
      else       { asm volatile("s_waitcnt vmcnt(0)" ::: "memory"); }
      __builtin_amdgcn_s_barrier();              // buf[(t+1)&1] ready for all
    }
  }
#undef STAGEB

  // cross-lane reduce over c (16 col-lanes), then one partial per row
#pragma unroll
  for (int m = 1; m < 16; m <<= 1)
#pragma unroll
    for (int mt = 0; mt < 4; ++mt)
#pragma unroll
      for (int r = 0; r < 4; ++r) rs[mt][r] += __shfl_xor(rs[mt][r], m, 64);

  if (c == 0) {
#pragma unroll
    for (int mt = 0; mt < 4; ++mt)
#pragma unroll
      for (int r = 0; r < 4; ++r)
        partial[(size_t)(wrowg + mt * 16 + g * 4 + r) * 16 + cs] = rs[mt][r];
  }
}

// ---------------- per-row: sum 16 partials + log - diag; block sums ----------------
__global__ __launch_bounds__(256) void rowfinal_kernel(
    const float* __restrict__ partial, const float* __restrict__ diagdot,
    float* __restrict__ blocksum)
{
  int row = blockIdx.x * 256 + threadIdx.x;
  const f32x4* p = (const f32x4*)(partial + (size_t)row * 16);
  f32x4 v0 = p[0], v1 = p[1], v2 = p[2], v3 = p[3];
  float s = (v0[0] + v0[1] + v0[2] + v0[3]) + (v1[0] + v1[1] + v1[2] + v1[3])
          + (v2[0] + v2[1] + v2[2] + v2[3]) + (v3[0] + v3[1] + v3[2] + v3[3]);
  // diagdot = kappa * s_ii ; need s_ii * TAU_INV = diagdot * ln2
  float term = logf(s + EPS) - diagdot[row] * LN2;
#pragma unroll
  for (int m = 1; m < 64; m <<= 1) term += __shfl_xor(term, m, 64);
  __shared__ float part[4];
  if ((threadIdx.x & 63) == 0) part[threadIdx.x >> 6] = term;
  __syncthreads();
  if (threadIdx.x == 0) blocksum[blockIdx.x] = part[0] + part[1] + part[2] + part[3];
}

// ---------------- final mean over 32 block sums ----------------
__global__ __launch_bounds__(64) void final_kernel(const float* __restrict__ blocksum,
                                                   float* __restrict__ out)
{
  int tid = threadIdx.x;
  float s = tid < 32 ? blocksum[tid] : 0.f;
#pragma unroll
  for (int m = 1; m < 64; m <<= 1) s += __shfl_xor(s, m, 64);
  if (tid == 0) out[0] = s * (1.0f / NROWS);
}

extern "C" void kernel_launch(void* const* d_in, const int* in_sizes, int n_in,
                              void* d_out, int out_size, void* d_ws, size_t ws_size,
                              hipStream_t stream) {
  const float* z1  = (const float*)d_in[0];
  const float* z2  = (const float*)d_in[1];
  const float* W1c = (const float*)d_in[2];
  const float* b1c = (const float*)d_in[3];
  const float* W2c = (const float*)d_in[4];
  const float* b2c = (const float*)d_in[5];
  const float* W1k = (const float*)d_in[6];
  const float* b1k = (const float*)d_in[7];
  const float* W2k = (const float*)d_in[8];
  const float* b2k = (const float*)d_in[9];

  char* ws = (char*)d_ws;
  bf16*  aU       = (bf16*)(ws);
  bf16*  bU       = (bf16*)(ws + (size_t)4  * 1024 * 1024);
  float* partial  = (float*)(ws + (size_t)8  * 1024 * 1024);   // 8192*16 f32 = 512 KB
  float* diagdot  = (float*)(ws + (size_t)9  * 1024 * 1024);   // 8192 f32
  float* blocksum = (float*)(ws + (size_t)10 * 1024 * 1024);   // 32 f32
  bf16*  wq       = (bf16*)(ws + (size_t)11 * 1024 * 1024);    // 4*65536 bf16

  cast4_kernel<<<dim3(64, 4), 256, 0, stream>>>(W1c, W2c, W1k, W2k, wq);

  mlp_norm_kernel<<<dim3(NROWS / 64, 2), 256, 0, stream>>>(
      z1, z2, wq, b1c, b2c, b1k, b2k, aU, bU);

  lse_kernel<<<dim3(512), 256, 0, stream>>>(aU, bU, partial, diagdot);

  rowfinal_kernel<<<32, 256, 0, stream>>>(partial, diagdot, blocksum);
  final_kernel<<<1, 64, 0, stream>>>(blocksum, (float*)d_out);
}

// Round 7
// 131.512 us; speedup vs baseline: 1.5419x; 1.5419x over previous
//
#include <hip/hip_runtime.h>

typedef __bf16 bf16;
typedef __bf16 bf16x8 __attribute__((ext_vector_type(8)));
typedef __bf16 bf16x4v __attribute__((ext_vector_type(4)));
typedef float  f32x4  __attribute__((ext_vector_type(4)));

#define NROWS 8192
#define DDIM  256
#define TAU_INV 2.0f
#define KAPPA 2.8853900817779268f   // TAU_INV * log2(e): A pre-scale so exp(s*2) = exp2(acc)
#define LN2 0.6931471805599453f
#define EPS 1e-8f

#define AS1C(p) ((const __attribute__((address_space(1))) void*)(p))
#define AS3(p)  ((__attribute__((address_space(3))) void*)(p))

// ---------------- cast 4 weight matrices fp32 -> bf16 ----------------
__global__ __launch_bounds__(256) void cast4_kernel(
    const float* __restrict__ s0, const float* __restrict__ s1,
    const float* __restrict__ s2, const float* __restrict__ s3,
    bf16* __restrict__ dst) {
  const float* s = blockIdx.y == 0 ? s0 : blockIdx.y == 1 ? s1 : blockIdx.y == 2 ? s2 : s3;
  bf16* d = dst + (size_t)blockIdx.y * 65536;
  int i = blockIdx.x * 256 + threadIdx.x;
  f32x4 v = ((const f32x4*)s)[i];
  bf16x4v o;
  o[0] = (bf16)v[0]; o[1] = (bf16)v[1]; o[2] = (bf16)v[2]; o[3] = (bf16)v[3];
  ((bf16x4v*)d)[i] = o;
}

// ---------------- fused cast + 2-layer MLP + row-normalize ----------------
// grid (NROWS/64, 2), block 256. Wave w owns rows [w*16, w*16+16).
// view 0 output (A side of the big GEMM) is scaled by KAPPA.
__global__ __launch_bounds__(256) void mlp_norm_kernel(
    const float* __restrict__ z1f, const float* __restrict__ z2f,
    const bf16* __restrict__ wq,
    const float* __restrict__ b1c, const float* __restrict__ b2c,
    const float* __restrict__ b1k, const float* __restrict__ b2k,
    bf16* __restrict__ outA, bf16* __restrict__ outB)
{
  const int view = blockIdx.y;
  const float* xf = view ? z2f : z1f;
  const bf16*  w1 = wq + (size_t)view * 131072;
  const bf16*  w2 = w1 + 65536;
  const float* b1 = view ? b1k : b1c;
  const float* b2 = view ? b2k : b2c;
  bf16* out = view ? outB : outA;
  const float osc = view ? 1.0f : KAPPA;

  __shared__ __align__(16) char xs[64 * 512];  // 64 rows x 256 bf16, XOR-swizzled

  const int tid  = threadIdx.x;
  const int lane = tid & 63;
  const int w    = tid >> 6;
  const int c    = lane & 15;
  const int g    = lane >> 4;
  const int r0   = blockIdx.x * 64;

#pragma unroll
  for (int k = 0; k < 8; ++k) {
    int gid = k * 256 + tid;
    int row = gid >> 5, cg = gid & 31;
    const f32x4* p = (const f32x4*)(xf + (size_t)(r0 + row) * DDIM + cg * 8);
    f32x4 v0 = p[0], v1 = p[1];
    bf16x8 o;
    o[0] = (bf16)v0[0]; o[1] = (bf16)v0[1]; o[2] = (bf16)v0[2]; o[3] = (bf16)v0[3];
    o[4] = (bf16)v1[0]; o[5] = (bf16)v1[1]; o[6] = (bf16)v1[2]; o[7] = (bf16)v1[3];
    *(bf16x8*)(xs + row * 512 + ((cg * 16) ^ ((row & 7) << 4))) = o;
  }
  __syncthreads();

  float b1v[16], b2v[16];
#pragma unroll
  for (int ct = 0; ct < 16; ++ct) { b1v[ct] = b1[ct * 16 + c]; b2v[ct] = b2[ct * 16 + c]; }

  const int arow = w * 16 + c;
  const int aswz = (arow & 7) << 4;

  f32x4 acc[16];
  const f32x4 fz = {0.f, 0.f, 0.f, 0.f};
#pragma unroll
  for (int ct = 0; ct < 16; ++ct) acc[ct] = fz;

#pragma unroll
  for (int ks = 0; ks < 8; ++ks) {
    bf16x8 af = *(const bf16x8*)(xs + arow * 512 + ((ks * 64 + g * 16) ^ aswz));
#pragma unroll
    for (int ct = 0; ct < 16; ++ct) {
      bf16x8 bfv = *(const bf16x8*)(w1 + (size_t)(ct * 16 + c) * DDIM + ks * 32 + g * 8);
      acc[ct] = __builtin_amdgcn_mfma_f32_16x16x32_bf16(af, bfv, acc[ct], 0, 0, 0);
    }
  }

#pragma unroll
  for (int ct = 0; ct < 16; ++ct) {
#pragma unroll
    for (int r = 0; r < 4; ++r) {
      float pre = acc[ct][r] + b1v[ct];
      float h = pre > 0.0f ? pre : (__expf(pre) - 1.0f);
      int row_l = w * 16 + g * 4 + r;
      int cb = (ct * 16 + c) * 2;
      *(bf16*)(xs + row_l * 512 + (cb ^ ((row_l & 7) << 4))) = (bf16)h;
    }
  }

#pragma unroll
  for (int ct = 0; ct < 16; ++ct) acc[ct] = fz;

#pragma unroll
  for (int ks = 0; ks < 8; ++ks) {
    bf16x8 af = *(const bf16x8*)(xs + arow * 512 + ((ks * 64 + g * 16) ^ aswz));
#pragma unroll
    for (int ct = 0; ct < 16; ++ct) {
      bf16x8 bfv = *(const bf16x8*)(w2 + (size_t)(ct * 16 + c) * DDIM + ks * 32 + g * 8);
      acc[ct] = __builtin_amdgcn_mfma_f32_16x16x32_bf16(af, bfv, acc[ct], 0, 0, 0);
    }
  }

  float ss[4] = {0.f, 0.f, 0.f, 0.f};
#pragma unroll
  for (int ct = 0; ct < 16; ++ct)
#pragma unroll
    for (int r = 0; r < 4; ++r) {
      float z = acc[ct][r] + b2v[ct];
      acc[ct][r] = z;
      ss[r] += z * z;
    }
#pragma unroll
  for (int m = 1; m < 16; m <<= 1)
#pragma unroll
    for (int r = 0; r < 4; ++r) ss[r] += __shfl_xor(ss[r], m, 64);

  float rinv[4];
#pragma unroll
  for (int r = 0; r < 4; ++r) rinv[r] = osc / sqrtf(ss[r]);

#pragma unroll
  for (int ct = 0; ct < 16; ++ct)
#pragma unroll
    for (int r = 0; r < 4; ++r) {
      int grow = r0 + w * 16 + g * 4 + r;
      out[(size_t)grow * DDIM + ct * 16 + c] = (bf16)(acc[ct][r] * rinv[r]);
    }
}

// ---------------- flash-style LSE: A-in-registers, B-tile loop ----------------
// grid 512 = 32 rb x 16 cs (XCD-patched). block 256 (4 waves); wave owns 64 rows.
// A is pre-scaled by KAPPA so sum += exp2(acc) directly (no mul).
// launch_bounds (256,1): needs ~245 VGPR; (256,2) empirically caps at 128 -> spill (r4/r6).
__global__ __launch_bounds__(256, 1) void lse_kernel(
    const bf16* __restrict__ A, const bf16* __restrict__ B,
    float* __restrict__ partial, float* __restrict__ diagdot)
{
  __shared__ __align__(16) char lds[65536];

  const int fid = blockIdx.x;
  const int xcd = fid & 7;
  const int l   = fid >> 3;
  const int rb  = (xcd >> 1) * 8 + (l >> 3);   // 8rb x 8cs patch per XCD: 3 MB <= L2
  const int cs  = (xcd & 1) * 8 + (l & 7);

  const int tid  = threadIdx.x;
  const int lane = tid & 63;
  const int w    = tid >> 6;
  const int c    = lane & 15;
  const int g    = lane >> 4;
  const int brow  = rb * 256;
  const int bcol0 = cs * 512;
  const int wrowg = brow + w * 64;             // wave's first global row
  const int td    = 4 * (rb & 1) + w;          // diag tile index (if diagblk)
  const bool diagblk = (cs == (rb >> 1));
  const int rswz  = (c & 7) << 4;

#define STAGEB(ttt)                                                                  \
  {                                                                                  \
    const int bsel_ = ((ttt) & 1) * 32768;                                           \
    _Pragma("unroll")                                                                \
    for (int it = 0; it < 8; ++it) {                                                 \
      int slot = it * 256 + tid;                                                     \
      int row = slot >> 5, q = slot & 31;                                            \
      const bf16* src = B + (size_t)(bcol0 + (ttt) * 64 + row) * DDIM                \
                        + ((q ^ (row & 7)) << 3);                                    \
      __builtin_amdgcn_global_load_lds(AS1C(src),                                    \
          AS3(lds + bsel_ + (it * 256 + w * 64) * 16), 16, 0, 0);                    \
    }                                                                                \
  }

  STAGEB(0);

  // A fragments: 64 rows x K=256 per wave, persistent in registers (128 VGPR)
  bf16x8 af[4][8];
#pragma unroll
  for (int mt = 0; mt < 4; ++mt)
#pragma unroll
    for (int kk = 0; kk < 8; ++kk)
      af[mt][kk] = *(const bf16x8*)(A + (size_t)(wrowg + mt * 16 + c) * DDIM + kk * 32 + g * 8);

  STAGEB(1);
  asm volatile("s_waitcnt vmcnt(8)" ::: "memory");   // A + B0 landed; B1 in flight
  __builtin_amdgcn_s_barrier();

  float rs[4][4];
#pragma unroll
  for (int mt = 0; mt < 4; ++mt)
#pragma unroll
    for (int r = 0; r < 4; ++r) rs[mt][r] = 0.f;

  const f32x4 fz = {0.f, 0.f, 0.f, 0.f};

#pragma unroll
  for (int t = 0; t < 8; ++t) {
    const char* bb = lds + (t & 1) * 32768;
    f32x4 acc[4][4];
#pragma unroll
    for (int mt = 0; mt < 4; ++mt)
#pragma unroll
      for (int nt = 0; nt < 4; ++nt) acc[mt][nt] = fz;

#pragma unroll
    for (int kk = 0; kk < 8; ++kk) {
      bf16x8 bv[4];
#pragma unroll
      for (int nt = 0; nt < 4; ++nt)
        bv[nt] = *(const bf16x8*)(bb + (nt * 16 + c) * 512 + ((kk * 64 + g * 16) ^ rswz));
#pragma unroll
      for (int mt = 0; mt < 4; ++mt)
#pragma unroll
        for (int nt = 0; nt < 4; ++nt)
          acc[mt][nt] = __builtin_amdgcn_mfma_f32_16x16x32_bf16(af[mt][kk], bv[nt], acc[mt][nt], 0, 0, 0);
    }

    // double-buffer handoff: overlap exp-fold with next-next tile staging
    if (t < 7) {
      __builtin_amdgcn_s_barrier();              // all waves done reading buf[t&1]
      if (t < 6) STAGEB(t + 2);                  // overwrite buf[t&1]
    }

    // diag extraction — STATIC vector indices only (rule #20)
    if (diagblk && t == td && (c >> 2) == g) {
#pragma unroll
      for (int mt = 0; mt < 4; ++mt) {
        f32x4 a = acc[mt][mt];
        int r = c & 3;
        float dv = (r == 0) ? a[0] : (r == 1) ? a[1] : (r == 2) ? a[2] : a[3];
        diagdot[wrowg + mt * 16 + c] = dv;
      }
    }

    // fold: per-lane partial row sums; acc is already kappa*s -> exp2 direct
#pragma unroll
    for (int mt = 0; mt < 4; ++mt)
#pragma unroll
      for (int nt = 0; nt < 4; ++nt)
#pragma unroll
        for (int r = 0; r < 4; ++r)
          rs[mt][r] += __builtin_amdgcn_exp2f(acc[mt][nt][r]);

    if (t < 7) {
      if (t < 6) { asm volatile("s_waitcnt vmcnt(8)" ::: "memory"); }
      else       { asm volatile("s_waitcnt vmcnt(0)" ::: "memory"); }
      __builtin_amdgcn_s_barrier();              // buf[(t+1)&1] ready for all
    }
  }
#undef STAGEB

  // cross-lane reduce over c (16 col-lanes), then one partial per row
#pragma unroll
  for (int m = 1; m < 16; m <<= 1)
#pragma unroll
    for (int mt = 0; mt < 4; ++mt)
#pragma unroll
      for (int r = 0; r < 4; ++r) rs[mt][r] += __shfl_xor(rs[mt][r], m, 64);

  if (c == 0) {
#pragma unroll
    for (int mt = 0; mt < 4; ++mt)
#pragma unroll
      for (int r = 0; r < 4; ++r)
        partial[(size_t)(wrowg + mt * 16 + g * 4 + r) * 16 + cs] = rs[mt][r];
  }
}

// ---------------- per-row: sum 16 partials + log - diag; block sums ----------------
__global__ __launch_bounds__(256) void rowfinal_kernel(
    const float* __restrict__ partial, const float* __restrict__ diagdot,
    float* __restrict__ blocksum)
{
  int row = blockIdx.x * 256 + threadIdx.x;
  const f32x4* p = (const f32x4*)(partial + (size_t)row * 16);
  f32x4 v0 = p[0], v1 = p[1], v2 = p[2], v3 = p[3];
  float s = (v0[0] + v0[1] + v0[2] + v0[3]) + (v1[0] + v1[1] + v1[2] + v1[3])
          + (v2[0] + v2[1] + v2[2] + v2[3]) + (v3[0] + v3[1] + v3[2] + v3[3]);
  // diagdot = kappa * s_ii ; need s_ii * TAU_INV = diagdot * ln2
  float term = logf(s + EPS) - diagdot[row] * LN2;
#pragma unroll
  for (int m = 1; m < 64; m <<= 1) term += __shfl_xor(term, m, 64);
  __shared__ float part[4];
  if ((threadIdx.x & 63) == 0) part[threadIdx.x >> 6] = term;
  __syncthreads();
  if (threadIdx.x == 0) blocksum[blockIdx.x] = part[0] + part[1] + part[2] + part[3];
}

// ---------------- final mean over 32 block sums ----------------
__global__ __launch_bounds__(64) void final_kernel(const float* __restrict__ blocksum,
                                                   float* __restrict__ out)
{
  int tid = threadIdx.x;
  float s = tid < 32 ? blocksum[tid] : 0.f;
#pragma unroll
  for (int m = 1; m < 64; m <<= 1) s += __shfl_xor(s, m, 64);
  if (tid == 0) out[0] = s * (1.0f / NROWS);
}

extern "C" void kernel_launch(void* const* d_in, const int* in_sizes, int n_in,
                              void* d_out, int out_size, void* d_ws, size_t ws_size,
                              hipStream_t stream) {
  const float* z1  = (const float*)d_in[0];
  const float* z2  = (const float*)d_in[1];
  const float* W1c = (const float*)d_in[2];
  const float* b1c = (const float*)d_in[3];
  const float* W2c = (const float*)d_in[4];
  const float* b2c = (const float*)d_in[5];
  const float* W1k = (const float*)d_in[6];
  const float* b1k = (const float*)d_in[7];
  const float* W2k = (const float*)d_in[8];
  const float* b2k = (const float*)d_in[9];

  char* ws = (char*)d_ws;
  bf16*  aU       = (bf16*)(ws);
  bf16*  bU       = (bf16*)(ws + (size_t)4  * 1024 * 1024);
  float* partial  = (float*)(ws + (size_t)8  * 1024 * 1024);   // 8192*16 f32 = 512 KB
  float* diagdot  = (float*)(ws + (size_t)9  * 1024 * 1024);   // 8192 f32
  float* blocksum = (float*)(ws + (size_t)10 * 1024 * 1024);   // 32 f32
  bf16*  wq       = (bf16*)(ws + (size_t)11 * 1024 * 1024);    // 4*65536 bf16

  cast4_kernel<<<dim3(64, 4), 256, 0, stream>>>(W1c, W2c, W1k, W2k, wq);

  mlp_norm_kernel<<<dim3(NROWS / 64, 2), 256, 0, stream>>>(
      z1, z2, wq, b1c, b2c, b1k, b2k, aU, bU);

  lse_kernel<<<dim3(512), 256, 0, stream>>>(aU, bU, partial, diagdot);

  rowfinal_kernel<<<32, 256, 0, stream>>>(partial, diagdot, blocksum);
  final_kernel<<<1, 64, 0, stream>>>(blocksum, (float*)d_out);
}

// Round 8
// 125.466 us; speedup vs baseline: 1.6162x; 1.0482x over previous
//
#include <hip/hip_runtime.h>

typedef __bf16 bf16;
typedef __bf16 bf16x8 __attribute__((ext_vector_type(8)));
typedef __bf16 bf16x4v __attribute__((ext_vector_type(4)));
typedef float  f32x4  __attribute__((ext_vector_type(4)));

#define NROWS 8192
#define DDIM  256
#define TAU_INV 2.0f
#define KAPPA 2.8853900817779268f   // TAU_INV * log2(e): A pre-scale so exp(s*2) = exp2(acc)
#define LN2 0.6931471805599453f
#define EPS 1e-8f

#define AS1C(p) ((const __attribute__((address_space(1))) void*)(p))
#define AS3(p)  ((__attribute__((address_space(3))) void*)(p))

// ---------------- cast 4 weight matrices fp32 -> bf16 ----------------
__global__ __launch_bounds__(256) void cast4_kernel(
    const float* __restrict__ s0, const float* __restrict__ s1,
    const float* __restrict__ s2, const float* __restrict__ s3,
    bf16* __restrict__ dst) {
  const float* s = blockIdx.y == 0 ? s0 : blockIdx.y == 1 ? s1 : blockIdx.y == 2 ? s2 : s3;
  bf16* d = dst + (size_t)blockIdx.y * 65536;
  int i = blockIdx.x * 256 + threadIdx.x;
  f32x4 v = ((const f32x4*)s)[i];
  bf16x4v o;
  o[0] = (bf16)v[0]; o[1] = (bf16)v[1]; o[2] = (bf16)v[2]; o[3] = (bf16)v[3];
  ((bf16x4v*)d)[i] = o;
}

// ---------------- fused cast + 2-layer MLP + row-normalize ----------------
// grid (NROWS/64, 2), block 256. Wave w owns rows [w*16, w*16+16).
// view 0 output (A side of the big GEMM) is scaled by KAPPA.
__global__ __launch_bounds__(256) void mlp_norm_kernel(
    const float* __restrict__ z1f, const float* __restrict__ z2f,
    const bf16* __restrict__ wq,
    const float* __restrict__ b1c, const float* __restrict__ b2c,
    const float* __restrict__ b1k, const float* __restrict__ b2k,
    bf16* __restrict__ outA, bf16* __restrict__ outB)
{
  const int view = blockIdx.y;
  const float* xf = view ? z2f : z1f;
  const bf16*  w1 = wq + (size_t)view * 131072;
  const bf16*  w2 = w1 + 65536;
  const float* b1 = view ? b1k : b1c;
  const float* b2 = view ? b2k : b2c;
  bf16* out = view ? outB : outA;
  const float osc = view ? 1.0f : KAPPA;

  __shared__ __align__(16) char xs[64 * 512];  // 64 rows x 256 bf16, XOR-swizzled

  const int tid  = threadIdx.x;
  const int lane = tid & 63;
  const int w    = tid >> 6;
  const int c    = lane & 15;
  const int g    = lane >> 4;
  const int r0   = blockIdx.x * 64;

#pragma unroll
  for (int k = 0; k < 8; ++k) {
    int gid = k * 256 + tid;
    int row = gid >> 5, cg = gid & 31;
    const f32x4* p = (const f32x4*)(xf + (size_t)(r0 + row) * DDIM + cg * 8);
    f32x4 v0 = p[0], v1 = p[1];
    bf16x8 o;
    o[0] = (bf16)v0[0]; o[1] = (bf16)v0[1]; o[2] = (bf16)v0[2]; o[3] = (bf16)v0[3];
    o[4] = (bf16)v1[0]; o[5] = (bf16)v1[1]; o[6] = (bf16)v1[2]; o[7] = (bf16)v1[3];
    *(bf16x8*)(xs + row * 512 + ((cg * 16) ^ ((row & 7) << 4))) = o;
  }
  __syncthreads();

  float b1v[16], b2v[16];
#pragma unroll
  for (int ct = 0; ct < 16; ++ct) { b1v[ct] = b1[ct * 16 + c]; b2v[ct] = b2[ct * 16 + c]; }

  const int arow = w * 16 + c;
  const int aswz = (arow & 7) << 4;

  f32x4 acc[16];
  const f32x4 fz = {0.f, 0.f, 0.f, 0.f};
#pragma unroll
  for (int ct = 0; ct < 16; ++ct) acc[ct] = fz;

#pragma unroll
  for (int ks = 0; ks < 8; ++ks) {
    bf16x8 af = *(const bf16x8*)(xs + arow * 512 + ((ks * 64 + g * 16) ^ aswz));
#pragma unroll
    for (int ct = 0; ct < 16; ++ct) {
      bf16x8 bfv = *(const bf16x8*)(w1 + (size_t)(ct * 16 + c) * DDIM + ks * 32 + g * 8);
      acc[ct] = __builtin_amdgcn_mfma_f32_16x16x32_bf16(af, bfv, acc[ct], 0, 0, 0);
    }
  }

#pragma unroll
  for (int ct = 0; ct < 16; ++ct) {
#pragma unroll
    for (int r = 0; r < 4; ++r) {
      float pre = acc[ct][r] + b1v[ct];
      float h = pre > 0.0f ? pre : (__expf(pre) - 1.0f);
      int row_l = w * 16 + g * 4 + r;
      int cb = (ct * 16 + c) * 2;
      *(bf16*)(xs + row_l * 512 + (cb ^ ((row_l & 7) << 4))) = (bf16)h;
    }
  }

#pragma unroll
  for (int ct = 0; ct < 16; ++ct) acc[ct] = fz;

#pragma unroll
  for (int ks = 0; ks < 8; ++ks) {
    bf16x8 af = *(const bf16x8*)(xs + arow * 512 + ((ks * 64 + g * 16) ^ aswz));
#pragma unroll
    for (int ct = 0; ct < 16; ++ct) {
      bf16x8 bfv = *(const bf16x8*)(w2 + (size_t)(ct * 16 + c) * DDIM + ks * 32 + g * 8);
      acc[ct] = __builtin_amdgcn_mfma_f32_16x16x32_bf16(af, bfv, acc[ct], 0, 0, 0);
    }
  }

  float ss[4] = {0.f, 0.f, 0.f, 0.f};
#pragma unroll
  for (int ct = 0; ct < 16; ++ct)
#pragma unroll
    for (int r = 0; r < 4; ++r) {
      float z = acc[ct][r] + b2v[ct];
      acc[ct][r] = z;
      ss[r] += z * z;
    }
#pragma unroll
  for (int m = 1; m < 16; m <<= 1)
#pragma unroll
    for (int r = 0; r < 4; ++r) ss[r] += __shfl_xor(ss[r], m, 64);

  float rinv[4];
#pragma unroll
  for (int r = 0; r < 4; ++r) rinv[r] = osc / sqrtf(ss[r]);

#pragma unroll
  for (int ct = 0; ct < 16; ++ct)
#pragma unroll
    for (int r = 0; r < 4; ++r) {
      int grow = r0 + w * 16 + g * 4 + r;
      out[(size_t)grow * DDIM + ct * 16 + c] = (bf16)(acc[ct][r] * rinv[r]);
    }
}

// ---------------- flash-style LSE: A-in-registers, B-tile loop ----------------
// grid 1024 = 64 rb x 16 cs (XCD patch 16rb x 8cs = 1MB A + 2MB B <= L2).
// block 256 (4 waves); wave owns 32 rows (af[2][8]=64 VGPR). Block: 128 rows x
// 512 cols (8 B-tiles of 64). Total VGPR ~160 -> no spill (r7 spilled at 254+).
__global__ __launch_bounds__(256, 1) void lse_kernel(
    const bf16* __restrict__ A, const bf16* __restrict__ B,
    float* __restrict__ partial, float* __restrict__ diagdot)
{
  __shared__ __align__(16) char lds[65536];

  const int fid = blockIdx.x;
  const int xcd = fid & 7;
  const int l   = fid >> 3;                    // 0..127
  const int rb  = (xcd >> 1) * 16 + (l >> 3);  // 0..63
  const int cs  = (xcd & 1) * 8 + (l & 7);     // 0..15

  const int tid  = threadIdx.x;
  const int lane = tid & 63;
  const int w    = tid >> 6;
  const int c    = lane & 15;
  const int g    = lane >> 4;
  const int brow  = rb * 128;
  const int bcol0 = cs * 512;
  const int wrowg = brow + w * 32;             // wave's first global row
  const int td    = 2 * (rb & 3) + (w >> 1);   // diag tile index (if diagblk)
  const bool diagblk = (cs == (rb >> 2));
  const int rswz  = (c & 7) << 4;

#define STAGEB(ttt)                                                                  \
  {                                                                                  \
    const int bsel_ = ((ttt) & 1) * 32768;                                           \
    _Pragma("unroll")                                                                \
    for (int it = 0; it < 8; ++it) {                                                 \
      int slot = it * 256 + tid;                                                     \
      int row = slot >> 5, q = slot & 31;                                            \
      const bf16* src = B + (size_t)(bcol0 + (ttt) * 64 + row) * DDIM                \
                        + ((q ^ (row & 7)) << 3);                                    \
      __builtin_amdgcn_global_load_lds(AS1C(src),                                    \
          AS3(lds + bsel_ + (it * 256 + w * 64) * 16), 16, 0, 0);                    \
    }                                                                                \
  }

  STAGEB(0);

  // A fragments: 32 rows x K=256 per wave, persistent in registers (64 VGPR)
  bf16x8 af[2][8];
#pragma unroll
  for (int mt = 0; mt < 2; ++mt)
#pragma unroll
    for (int kk = 0; kk < 8; ++kk)
      af[mt][kk] = *(const bf16x8*)(A + (size_t)(wrowg + mt * 16 + c) * DDIM + kk * 32 + g * 8);

  STAGEB(1);
  asm volatile("s_waitcnt vmcnt(8)" ::: "memory");   // B0 + af landed; B1 in flight
  __builtin_amdgcn_s_barrier();

  float rs[2][4];
#pragma unroll
  for (int mt = 0; mt < 2; ++mt)
#pragma unroll
    for (int r = 0; r < 4; ++r) rs[mt][r] = 0.f;

  const f32x4 fz = {0.f, 0.f, 0.f, 0.f};

#pragma unroll
  for (int t = 0; t < 8; ++t) {
    const char* bb = lds + (t & 1) * 32768;
    f32x4 acc[2][4];
#pragma unroll
    for (int mt = 0; mt < 2; ++mt)
#pragma unroll
      for (int nt = 0; nt < 4; ++nt) acc[mt][nt] = fz;

#pragma unroll
    for (int kk = 0; kk < 8; ++kk) {
      bf16x8 bv[4];
#pragma unroll
      for (int nt = 0; nt < 4; ++nt)
        bv[nt] = *(const bf16x8*)(bb + (nt * 16 + c) * 512 + ((kk * 64 + g * 16) ^ rswz));
#pragma unroll
      for (int mt = 0; mt < 2; ++mt)
#pragma unroll
        for (int nt = 0; nt < 4; ++nt)
          acc[mt][nt] = __builtin_amdgcn_mfma_f32_16x16x32_bf16(af[mt][kk], bv[nt], acc[mt][nt], 0, 0, 0);
    }

    // double-buffer handoff: overlap exp-fold with next-next tile staging
    if (t < 7) {
      __builtin_amdgcn_s_barrier();              // all waves done reading buf[t&1]
      if (t < 6) STAGEB(t + 2);                  // overwrite buf[t&1]
    }

    // diag extraction — STATIC vector indices only (rule #20).
    // wave rows sit at col offset (w&1)*32 within tile td -> nt = (w&1)*2 + mt.
    if (diagblk && t == td && (c >> 2) == g) {
#pragma unroll
      for (int mt = 0; mt < 2; ++mt) {
        f32x4 a = (w & 1) ? acc[mt][2 + mt] : acc[mt][mt];
        int r = c & 3;
        float dv = (r == 0) ? a[0] : (r == 1) ? a[1] : (r == 2) ? a[2] : a[3];
        diagdot[wrowg + mt * 16 + c] = dv;
      }
    }

    // fold: per-lane partial row sums; acc is already kappa*s -> exp2 direct
#pragma unroll
    for (int mt = 0; mt < 2; ++mt)
#pragma unroll
      for (int nt = 0; nt < 4; ++nt)
#pragma unroll
        for (int r = 0; r < 4; ++r)
          rs[mt][r] += __builtin_amdgcn_exp2f(acc[mt][nt][r]);

    if (t < 7) {
      if (t < 6) { asm volatile("s_waitcnt vmcnt(8)" ::: "memory"); }
      else       { asm volatile("s_waitcnt vmcnt(0)" ::: "memory"); }
      __builtin_amdgcn_s_barrier();              // buf[(t+1)&1] ready for all
    }
  }
#undef STAGEB

  // cross-lane reduce over c (16 col-lanes), then one partial per row
#pragma unroll
  for (int m = 1; m < 16; m <<= 1)
#pragma unroll
    for (int mt = 0; mt < 2; ++mt)
#pragma unroll
      for (int r = 0; r < 4; ++r) rs[mt][r] += __shfl_xor(rs[mt][r], m, 64);

  if (c == 0) {
#pragma unroll
    for (int mt = 0; mt < 2; ++mt)
#pragma unroll
      for (int r = 0; r < 4; ++r)
        partial[(size_t)(wrowg + mt * 16 + g * 4 + r) * 16 + cs] = rs[mt][r];
  }
}

// ---------------- per-row: sum 16 partials + log - diag; block sums ----------------
__global__ __launch_bounds__(256) void rowfinal_kernel(
    const float* __restrict__ partial, const float* __restrict__ diagdot,
    float* __restrict__ blocksum)
{
  int row = blockIdx.x * 256 + threadIdx.x;
  const f32x4* p = (const f32x4*)(partial + (size_t)row * 16);
  f32x4 v0 = p[0], v1 = p[1], v2 = p[2], v3 = p[3];
  float s = (v0[0] + v0[1] + v0[2] + v0[3]) + (v1[0] + v1[1] + v1[2] + v1[3])
          + (v2[0] + v2[1] + v2[2] + v2[3]) + (v3[0] + v3[1] + v3[2] + v3[3]);
  // diagdot = kappa * s_ii ; need s_ii * TAU_INV = diagdot * ln2
  float term = logf(s + EPS) - diagdot[row] * LN2;
#pragma unroll
  for (int m = 1; m < 64; m <<= 1) term += __shfl_xor(term, m, 64);
  __shared__ float part[4];
  if ((threadIdx.x & 63) == 0) part[threadIdx.x >> 6] = term;
  __syncthreads();
  if (threadIdx.x == 0) blocksum[blockIdx.x] = part[0] + part[1] + part[2] + part[3];
}

// ---------------- final mean over 32 block sums ----------------
__global__ __launch_bounds__(64) void final_kernel(const float* __restrict__ blocksum,
                                                   float* __restrict__ out)
{
  int tid = threadIdx.x;
  float s = tid < 32 ? blocksum[tid] : 0.f;
#pragma unroll
  for (int m = 1; m < 64; m <<= 1) s += __shfl_xor(s, m, 64);
  if (tid == 0) out[0] = s * (1.0f / NROWS);
}

extern "C" void kernel_launch(void* const* d_in, const int* in_sizes, int n_in,
                              void* d_out, int out_size, void* d_ws, size_t ws_size,
                              hipStream_t stream) {
  const float* z1  = (const float*)d_in[0];
  const float* z2  = (const float*)d_in[1];
  const float* W1c = (const float*)d_in[2];
  const float* b1c = (const float*)d_in[3];
  const float* W2c = (const float*)d_in[4];
  const float* b2c = (const float*)d_in[5];
  const float* W1k = (const float*)d_in[6];
  const float* b1k = (const float*)d_in[7];
  const float* W2k = (const float*)d_in[8];
  const float* b2k = (const float*)d_in[9];

  char* ws = (char*)d_ws;
  bf16*  aU       = (bf16*)(ws);
  bf16*  bU       = (bf16*)(ws + (size_t)4  * 1024 * 1024);
  float* partial  = (float*)(ws + (size_t)8  * 1024 * 1024);   // 8192*16 f32 = 512 KB
  float* diagdot  = (float*)(ws + (size_t)9  * 1024 * 1024);   // 8192 f32
  float* blocksum = (float*)(ws + (size_t)10 * 1024 * 1024);   // 32 f32
  bf16*  wq       = (bf16*)(ws + (size_t)11 * 1024 * 1024);    // 4*65536 bf16

  cast4_kernel<<<dim3(64, 4), 256, 0, stream>>>(W1c, W2c, W1k, W2k, wq);

  mlp_norm_kernel<<<dim3(NROWS / 64, 2), 256, 0, stream>>>(
      z1, z2, wq, b1c, b2c, b1k, b2k, aU, bU);

  lse_kernel<<<dim3(1024), 256, 0, stream>>>(aU, bU, partial, diagdot);

  rowfinal_kernel<<<32, 256, 0, stream>>>(partial, diagdot, blocksum);
  final_kernel<<<1, 64, 0, stream>>>(blocksum, (float*)d_out);
}

// Round 9
// 78.866 us; speedup vs baseline: 2.5712x; 1.5909x over previous
//
#include <hip/hip_runtime.h>

typedef __bf16 bf16;
typedef __bf16 bf16x8 __attribute__((ext_vector_type(8)));
typedef __bf16 bf16x4v __attribute__((ext_vector_type(4)));
typedef float  f32x4  __attribute__((ext_vector_type(4)));

#define NROWS 8192
#define DDIM  256
#define TAU_INV 2.0f
#define KAPPA 2.8853900817779268f   // TAU_INV * log2(e): A pre-scale so exp(s/tau) = exp2(acc)
#define LN2 0.6931471805599453f
#define EPS 1e-8f

#define AS1C(p) ((const __attribute__((address_space(1))) void*)(p))
#define AS3(p)  ((__attribute__((address_space(3))) void*)(p))

// ---------------- cast 4 weight matrices fp32 -> bf16 ----------------
__global__ __launch_bounds__(256) void cast4_kernel(
    const float* __restrict__ s0, const float* __restrict__ s1,
    const float* __restrict__ s2, const float* __restrict__ s3,
    bf16* __restrict__ dst) {
  const float* s = blockIdx.y == 0 ? s0 : blockIdx.y == 1 ? s1 : blockIdx.y == 2 ? s2 : s3;
  bf16* d = dst + (size_t)blockIdx.y * 65536;
  int i = blockIdx.x * 256 + threadIdx.x;
  f32x4 v = ((const f32x4*)s)[i];
  bf16x4v o;
  o[0] = (bf16)v[0]; o[1] = (bf16)v[1]; o[2] = (bf16)v[2]; o[3] = (bf16)v[3];
  ((bf16x4v*)d)[i] = o;
}

// ---------------- fused cast + 2-layer MLP + row-normalize (ct-split) ----------------
// grid (NROWS/64, 2), block 256 (4 waves). Wave w computes output cols
// [w*64, w*64+64) for ALL 64 rows -> weight reads 256KB/block (not 1MB), coalesced.
__global__ __launch_bounds__(256, 1) void mlp_norm_kernel(
    const float* __restrict__ z1f, const float* __restrict__ z2f,
    const bf16* __restrict__ wq,
    const float* __restrict__ b1c, const float* __restrict__ b2c,
    const float* __restrict__ b1k, const float* __restrict__ b2k,
    bf16* __restrict__ outA, bf16* __restrict__ outB)
{
  const int view = blockIdx.y;
  const float* xf = view ? z2f : z1f;
  const bf16*  w1 = wq + (size_t)view * 131072;
  const bf16*  w2 = w1 + 65536;
  const float* b1 = view ? b1k : b1c;
  const float* b2 = view ? b2k : b2c;
  bf16* out = view ? outB : outA;
  const float osc = view ? 1.0f : KAPPA;

  __shared__ __align__(16) char xs[64 * 512];   // x rows, XOR-swizzled
  __shared__ __align__(16) char hs[64 * 512];   // h rows, XOR-swizzled
  __shared__ float sspart[4][64];

  const int tid  = threadIdx.x;
  const int lane = tid & 63;
  const int w    = tid >> 6;
  const int c    = lane & 15;
  const int g    = lane >> 4;
  const int r0   = blockIdx.x * 64;
  const int colw = w * 64;

  // fused cast: load f32, convert, swizzled ds_write
#pragma unroll
  for (int k = 0; k < 8; ++k) {
    int gid = k * 256 + tid;
    int row = gid >> 5, cg = gid & 31;
    const f32x4* p = (const f32x4*)(xf + (size_t)(r0 + row) * DDIM + cg * 8);
    f32x4 v0 = p[0], v1 = p[1];
    bf16x8 o;
    o[0] = (bf16)v0[0]; o[1] = (bf16)v0[1]; o[2] = (bf16)v0[2]; o[3] = (bf16)v0[3];
    o[4] = (bf16)v1[0]; o[5] = (bf16)v1[1]; o[6] = (bf16)v1[2]; o[7] = (bf16)v1[3];
    *(bf16x8*)(xs + row * 512 + ((cg * 16) ^ ((row & 7) << 4))) = o;
  }
  __syncthreads();

  float b1v[4], b2v[4];
#pragma unroll
  for (int ct = 0; ct < 4; ++ct) {
    b1v[ct] = b1[colw + ct * 16 + c];
    b2v[ct] = b2[colw + ct * 16 + c];
  }

  const int aswz = (c & 7) << 4;
  f32x4 acc[4][4];                        // [ct][mt]
  const f32x4 fz = {0.f, 0.f, 0.f, 0.f};
#pragma unroll
  for (int ct = 0; ct < 4; ++ct)
#pragma unroll
    for (int mt = 0; mt < 4; ++mt) acc[ct][mt] = fz;

  // GEMM1: h_pre[all rows][wave's 64 cols] = x @ W1^T
#pragma unroll
  for (int ks = 0; ks < 8; ++ks) {
    bf16x8 af[4];
#pragma unroll
    for (int mt = 0; mt < 4; ++mt)
      af[mt] = *(const bf16x8*)(xs + (mt * 16 + c) * 512 + ((ks * 64 + g * 16) ^ aswz));
#pragma unroll
    for (int ct = 0; ct < 4; ++ct) {
      bf16x8 bfv = *(const bf16x8*)(w1 + (size_t)(colw + ct * 16 + c) * DDIM + ks * 32 + g * 8);
#pragma unroll
      for (int mt = 0; mt < 4; ++mt)
        acc[ct][mt] = __builtin_amdgcn_mfma_f32_16x16x32_bf16(af[mt], bfv, acc[ct][mt], 0, 0, 0);
    }
  }

  // ELU -> hs (wave writes cols colw..+64 of all rows; distinct bytes per wave)
#pragma unroll
  for (int ct = 0; ct < 4; ++ct)
#pragma unroll
    for (int mt = 0; mt < 4; ++mt)
#pragma unroll
      for (int r = 0; r < 4; ++r) {
        float pre = acc[ct][mt][r] + b1v[ct];
        float h = pre > 0.0f ? pre : (__expf(pre) - 1.0f);
        int row = mt * 16 + g * 4 + r;
        int cb = (colw + ct * 16 + c) * 2;
        *(bf16*)(hs + row * 512 + (cb ^ ((row & 7) << 4))) = (bf16)h;
      }
  __syncthreads();

#pragma unroll
  for (int ct = 0; ct < 4; ++ct)
#pragma unroll
    for (int mt = 0; mt < 4; ++mt) acc[ct][mt] = fz;

  // GEMM2: z[all rows][wave's 64 cols] = h @ W2^T
#pragma unroll
  for (int ks = 0; ks < 8; ++ks) {
    bf16x8 af[4];
#pragma unroll
    for (int mt = 0; mt < 4; ++mt)
      af[mt] = *(const bf16x8*)(hs + (mt * 16 + c) * 512 + ((ks * 64 + g * 16) ^ aswz));
#pragma unroll
    for (int ct = 0; ct < 4; ++ct) {
      bf16x8 bfv = *(const bf16x8*)(w2 + (size_t)(colw + ct * 16 + c) * DDIM + ks * 32 + g * 8);
#pragma unroll
      for (int mt = 0; mt < 4; ++mt)
        acc[ct][mt] = __builtin_amdgcn_mfma_f32_16x16x32_bf16(af[mt], bfv, acc[ct][mt], 0, 0, 0);
    }
  }

  // bias + per-wave row-norm partials (sum over this wave's 64 cols)
  float ss[4][4];                         // [mt][r]
#pragma unroll
  for (int mt = 0; mt < 4; ++mt)
#pragma unroll
    for (int r = 0; r < 4; ++r) ss[mt][r] = 0.f;
#pragma unroll
  for (int ct = 0; ct < 4; ++ct)
#pragma unroll
    for (int mt = 0; mt < 4; ++mt)
#pragma unroll
      for (int r = 0; r < 4; ++r) {
        float z = acc[ct][mt][r] + b2v[ct];
        acc[ct][mt][r] = z;
        ss[mt][r] += z * z;
      }
#pragma unroll
  for (int m = 1; m < 16; m <<= 1)
#pragma unroll
    for (int mt = 0; mt < 4; ++mt)
#pragma unroll
      for (int r = 0; r < 4; ++r) ss[mt][r] += __shfl_xor(ss[mt][r], m, 64);

  if (c == 0) {
#pragma unroll
    for (int mt = 0; mt < 4; ++mt)
#pragma unroll
      for (int r = 0; r < 4; ++r) sspart[w][mt * 16 + g * 4 + r] = ss[mt][r];
  }
  __syncthreads();

#pragma unroll
  for (int mt = 0; mt < 4; ++mt)
#pragma unroll
    for (int r = 0; r < 4; ++r) {
      int row = mt * 16 + g * 4 + r;
      float s = sspart[0][row] + sspart[1][row] + sspart[2][row] + sspart[3][row];
      float rinv = osc / sqrtf(s);
#pragma unroll
      for (int ct = 0; ct < 4; ++ct)
        out[(size_t)(r0 + row) * DDIM + colw + ct * 16 + c] = (bf16)(acc[ct][mt][r] * rinv);
    }
}

// ---------------- 128x128 tile LSE (round-1 proven structure) ----------------
// grid (64, 64), block 256 (4 waves, 2x2 of 64x64). LDS 32 KB single-buffered.
// A is KAPPA-prescaled -> epilogue sum += exp2(acc); diag extracted on bx==by.
__global__ __launch_bounds__(256, 2) void lse_kernel(
    const bf16* __restrict__ A, const bf16* __restrict__ B,
    float* __restrict__ partial, float* __restrict__ diagdot)
{
  __shared__ __align__(16) char As[128 * 128];  // 128 rows x 64 bf16, swizzled
  __shared__ __align__(16) char Bs[128 * 128];

  const int tid  = threadIdx.x;
  const int lane = tid & 63;
  const int w    = tid >> 6;
  const int c    = lane & 15;
  const int g    = lane >> 4;
  const int brow = blockIdx.y * 128;
  const int bcol = blockIdx.x * 128;
  const int wrow = (w >> 1) * 64;
  const int wcol = (w & 1) * 64;

  f32x4 acc[4][4];
  const f32x4 fz = {0.f, 0.f, 0.f, 0.f};
#pragma unroll
  for (int i = 0; i < 4; ++i)
#pragma unroll
    for (int j = 0; j < 4; ++j) acc[i][j] = fz;

  for (int kt = 0; kt < 4; ++kt) {
#pragma unroll
    for (int it = 0; it < 4; ++it) {
      int slot = it * 256 + tid;
      int row = slot >> 3, q = slot & 7;
      int col = kt * 64 + ((q ^ (row & 7)) * 8);
      __builtin_amdgcn_global_load_lds(AS1C(A + (size_t)(brow + row) * DDIM + col),
                                       AS3(As + (it * 256 + w * 64) * 16), 16, 0, 0);
      __builtin_amdgcn_global_load_lds(AS1C(B + (size_t)(bcol + row) * DDIM + col),
                                       AS3(Bs + (it * 256 + w * 64) * 16), 16, 0, 0);
    }
    __syncthreads();
#pragma unroll
    for (int sk = 0; sk < 2; ++sk) {
      bf16x8 af[4], bfv[4];
#pragma unroll
      for (int mt = 0; mt < 4; ++mt) {
        int rl = wrow + mt * 16 + c;
        af[mt] = *(const bf16x8*)(As + rl * 128 + ((sk * 64 + g * 16) ^ ((rl & 7) << 4)));
      }
#pragma unroll
      for (int ct = 0; ct < 4; ++ct) {
        int rl = wcol + ct * 16 + c;
        bfv[ct] = *(const bf16x8*)(Bs + rl * 128 + ((sk * 64 + g * 16) ^ ((rl & 7) << 4)));
      }
#pragma unroll
      for (int mt = 0; mt < 4; ++mt)
#pragma unroll
        for (int ct = 0; ct < 4; ++ct)
          acc[mt][ct] = __builtin_amdgcn_mfma_f32_16x16x32_bf16(af[mt], bfv[ct], acc[mt][ct], 0, 0, 0);
    }
    __syncthreads();
  }

  // diag: bx==by blocks, waves 0/3 (wrow==wcol), tiles ct==mt, lanes c==g*4+r
  if (blockIdx.x == blockIdx.y && (w == 0 || w == 3) && (c >> 2) == g) {
#pragma unroll
    for (int mt = 0; mt < 4; ++mt) {
      f32x4 a = acc[mt][mt];
      int r = c & 3;
      float dv = (r == 0) ? a[0] : (r == 1) ? a[1] : (r == 2) ? a[2] : a[3];
      diagdot[brow + wrow + mt * 16 + c] = dv;
    }
  }

  // epilogue: exp2(acc) (A pre-scaled by KAPPA), reduce over this wave's 64 cols
  float rs[4][4];
#pragma unroll
  for (int mt = 0; mt < 4; ++mt)
#pragma unroll
    for (int r = 0; r < 4; ++r) rs[mt][r] = 0.f;
#pragma unroll
  for (int mt = 0; mt < 4; ++mt)
#pragma unroll
    for (int ct = 0; ct < 4; ++ct)
#pragma unroll
      for (int r = 0; r < 4; ++r) rs[mt][r] += __builtin_amdgcn_exp2f(acc[mt][ct][r]);
#pragma unroll
  for (int m = 1; m < 16; m <<= 1)
#pragma unroll
    for (int mt = 0; mt < 4; ++mt)
#pragma unroll
      for (int r = 0; r < 4; ++r) rs[mt][r] += __shfl_xor(rs[mt][r], m, 64);

  if (c == 0) {
    int cb2 = blockIdx.x * 2 + (w & 1);
#pragma unroll
    for (int mt = 0; mt < 4; ++mt)
#pragma unroll
      for (int r = 0; r < 4; ++r) {
        int grow = brow + wrow + mt * 16 + g * 4 + r;
        partial[(size_t)grow * 128 + cb2] = rs[mt][r];
      }
  }
}

// ---------------- per-row: sum 128 partials + log - diag; block sums ----------------
__global__ __launch_bounds__(256) void rowfinal_kernel(
    const float* __restrict__ partial, const float* __restrict__ diagdot,
    float* __restrict__ blocksum)
{
  int row = blockIdx.x * 256 + threadIdx.x;
  const f32x4* p = (const f32x4*)(partial + (size_t)row * 128);
  float s = 0.f;
#pragma unroll 8
  for (int i = 0; i < 32; ++i) {
    f32x4 v = p[i];
    s += (v[0] + v[1]) + (v[2] + v[3]);
  }
  // diagdot = kappa * s_ii ; s_ii * TAU_INV = diagdot * ln2
  float term = logf(s + EPS) - diagdot[row] * LN2;
#pragma unroll
  for (int m = 1; m < 64; m <<= 1) term += __shfl_xor(term, m, 64);
  __shared__ float part[4];
  if ((threadIdx.x & 63) == 0) part[threadIdx.x >> 6] = term;
  __syncthreads();
  if (threadIdx.x == 0) blocksum[blockIdx.x] = part[0] + part[1] + part[2] + part[3];
}

// ---------------- final mean over 32 block sums ----------------
__global__ __launch_bounds__(64) void final_kernel(const float* __restrict__ blocksum,
                                                   float* __restrict__ out)
{
  int tid = threadIdx.x;
  float s = tid < 32 ? blocksum[tid] : 0.f;
#pragma unroll
  for (int m = 1; m < 64; m <<= 1) s += __shfl_xor(s, m, 64);
  if (tid == 0) out[0] = s * (1.0f / NROWS);
}

extern "C" void kernel_launch(void* const* d_in, const int* in_sizes, int n_in,
                              void* d_out, int out_size, void* d_ws, size_t ws_size,
                              hipStream_t stream) {
  const float* z1  = (const float*)d_in[0];
  const float* z2  = (const float*)d_in[1];
  const float* W1c = (const float*)d_in[2];
  const float* b1c = (const float*)d_in[3];
  const float* W2c = (const float*)d_in[4];
  const float* b2c = (const float*)d_in[5];
  const float* W1k = (const float*)d_in[6];
  const float* b1k = (const float*)d_in[7];
  const float* W2k = (const float*)d_in[8];
  const float* b2k = (const float*)d_in[9];

  char* ws = (char*)d_ws;
  bf16*  aU       = (bf16*)(ws);                               // 4 MB
  bf16*  bU       = (bf16*)(ws + (size_t)4  * 1024 * 1024);    // 4 MB
  float* partial  = (float*)(ws + (size_t)8  * 1024 * 1024);   // 8192*128 f32 = 4 MB
  float* diagdot  = (float*)(ws + (size_t)12 * 1024 * 1024);   // 32 KB
  float* blocksum = (float*)(ws + (size_t)12 * 1024 * 1024 + 64 * 1024);
  bf16*  wq       = (bf16*)(ws + (size_t)13 * 1024 * 1024);    // 512 KB

  cast4_kernel<<<dim3(64, 4), 256, 0, stream>>>(W1c, W2c, W1k, W2k, wq);

  mlp_norm_kernel<<<dim3(NROWS / 64, 2), 256, 0, stream>>>(
      z1, z2, wq, b1c, b2c, b1k, b2k, aU, bU);

  lse_kernel<<<dim3(NROWS / 128, NROWS / 128), 256, 0, stream>>>(aU, bU, partial, diagdot);

  rowfinal_kernel<<<32, 256, 0, stream>>>(partial, diagdot, blocksum);
  final_kernel<<<1, 64, 0, stream>>>(blocksum, (float*)d_out);
}